// Round 6
// baseline (723.919 us; speedup 1.0000x reference)
//
#include <hip/hip_runtime.h>
#include <math.h>

namespace {

constexpr int Bsz = 64;
constexpr int Nn  = 1024;
constexpr int Dd  = 512;
constexpr int BPB = 16;            // blocks per batch
constexpr int NBLK = Bsz * BPB;    // 1024 blocks
constexpr float SCALE = 0.044194173824159216f;  // 1/sqrt(512)

#define DOT8(va, vb, u1, u2) \
  ((va).x*(u1).x + (va).y*(u1).y + (va).z*(u1).z + (va).w*(u1).w + \
   (vb).x*(u2).x + (vb).y*(u2).y + (vb).z*(u2).z + (vb).w*(u2).w)

// Persistent pipelined kernel. Block (b,i): i = blk&15, b = blk>>4.
// Phase 1: colsum of rows [i*64, i*64+64) -> part (2 parity segments).
// Phase 2: [gate cnt1[b]==16] xbar -> kbar slice [i*32,+32) -> u-partial.
// Phase 3: [gate cnt2[b]==16] fused scores+exp-weighted sum over rows [i*64,+64).
// Phase 4: [gate cnt3[b]==16, i==0 only] softmax -> w; combine P -> agg.
// All cross-block data passes use store -> __threadfence -> atomicAdd(release)
// and spin(atomicAdd 0) -> __threadfence -> load (device scope, XCD-safe).
__global__ __launch_bounds__(256, 4) void k_all(const float* __restrict__ x,
                                                const float* __restrict__ Wq,
                                                const float* __restrict__ Wk,
                                                const float* __restrict__ bk,
                                                float* __restrict__ part,
                                                float* __restrict__ upart,
                                                float* __restrict__ s,
                                                float* __restrict__ P,
                                                float* __restrict__ w,
                                                float* __restrict__ agg,
                                                int* __restrict__ cnt1,
                                                int* __restrict__ cnt2,
                                                int* __restrict__ cnt3) {
  const int blk = blockIdx.x;
  const int b = blk >> 4, i = blk & 15;
  const int t = threadIdx.x;
  const int wave = t >> 6, lane = t & 63;

  __shared__ __align__(16) float xbar[Dd];
  __shared__ float kb[32];
  __shared__ __align__(16) float pacc[4][Dd];
  __shared__ float lred[4];

  // ---------- Phase 1: colsum ----------
  {
    const int col = (t & 127) * 4;   // 4 columns per thread
    const int p = t >> 7;            // row parity
    const float* xb = x + (size_t)b * Nn * Dd;
    float4 acc = make_float4(0.f, 0.f, 0.f, 0.f);
    #pragma unroll 8
    for (int j = 0; j < 32; ++j) {
      const int n = i * 64 + j * 2 + p;
      const float4 v = *reinterpret_cast<const float4*>(xb + (size_t)n * Dd + col);
      acc.x += v.x; acc.y += v.y; acc.z += v.z; acc.w += v.w;
    }
    *reinterpret_cast<float4*>(part + ((size_t)blk * 2 + p) * Dd + col) = acc;
  }
  __threadfence();
  __syncthreads();
  if (t == 0) atomicAdd(&cnt1[b], 1);

  // ---------- Phase 2: prep (kbar slice + u-partial) ----------
  if (t == 0) { while (atomicAdd(&cnt1[b], 0) < BPB) __builtin_amdgcn_s_sleep(8); }
  __syncthreads();
  __threadfence();
  {
    float a0 = 0.f, a1 = 0.f;
    const float* pb = part + (size_t)b * BPB * 2 * Dd;
    #pragma unroll 8
    for (int j = 0; j < 32; ++j) {
      a0 += pb[(size_t)j * Dd + t];
      a1 += pb[(size_t)j * Dd + t + 256];
    }
    xbar[t]       = a0 * (1.0f / Nn);
    xbar[t + 256] = a1 * (1.0f / Nn);
  }
  __syncthreads();
  {
    const float4 xv1 = *reinterpret_cast<const float4*>(xbar + lane * 4);
    const float4 xv2 = *reinterpret_cast<const float4*>(xbar + 256 + lane * 4);
    for (int jj = 0; jj < 8; jj += 2) {
      const int l0 = wave * 8 + jj, l1 = l0 + 1;
      const int e0 = i * 32 + l0, e1 = e0 + 1;
      const float4* r0 = reinterpret_cast<const float4*>(Wk + (size_t)e0 * Dd);
      const float4* r1 = reinterpret_cast<const float4*>(Wk + (size_t)e1 * Dd);
      const float4 a0 = r0[lane], b0 = r0[64 + lane];
      const float4 a1 = r1[lane], b1 = r1[64 + lane];
      float d0 = DOT8(a0, b0, xv1, xv2);
      float d1 = DOT8(a1, b1, xv1, xv2);
      #pragma unroll
      for (int off = 32; off > 0; off >>= 1) {
        d0 += __shfl_xor(d0, off);
        d1 += __shfl_xor(d1, off);
      }
      if (lane == 0) { kb[l0] = bk[e0] + d0; kb[l1] = bk[e1] + d1; }
    }
  }
  __syncthreads();
  {
    const float* Wbase = Wq + (size_t)(i * 32) * Dd;
    float b0 = 0.f, b1 = 0.f, b2 = 0.f, b3 = 0.f;
    #pragma unroll 4
    for (int e = 0; e < 32; e += 2) {
      const float k0 = kb[e], k1 = kb[e + 1];
      b0 += k0 * Wbase[(size_t)e * Dd + t];
      b1 += k0 * Wbase[(size_t)e * Dd + t + 256];
      b2 += k1 * Wbase[(size_t)(e + 1) * Dd + t];
      b3 += k1 * Wbase[(size_t)(e + 1) * Dd + t + 256];
    }
    float* ub = upart + (size_t)blk * Dd;
    ub[t]       = b0 + b2;
    ub[t + 256] = b1 + b3;
  }
  __threadfence();
  __syncthreads();
  if (t == 0) atomicAdd(&cnt2[b], 1);

  // ---------- Phase 3: fused scores + exp-weighted accumulate ----------
  if (t == 0) { while (atomicAdd(&cnt2[b], 0) < BPB) __builtin_amdgcn_s_sleep(8); }
  __syncthreads();
  __threadfence();
  {
    float4 u1 = make_float4(0.f, 0.f, 0.f, 0.f);
    float4 u2 = make_float4(0.f, 0.f, 0.f, 0.f);
    #pragma unroll
    for (int j = 0; j < BPB; ++j) {
      const float* ub = upart + (size_t)(b * BPB + j) * Dd;
      const float4 p1 = *reinterpret_cast<const float4*>(ub + lane * 4);
      const float4 p2 = *reinterpret_cast<const float4*>(ub + 256 + lane * 4);
      u1.x += p1.x; u1.y += p1.y; u1.z += p1.z; u1.w += p1.w;
      u2.x += p2.x; u2.y += p2.y; u2.z += p2.z; u2.w += p2.w;
    }

    const float* xb = x + ((size_t)b * Nn + (size_t)i * 64) * Dd;
    float* sb = s + (size_t)b * Nn + i * 64;
    float4 a1 = make_float4(0.f, 0.f, 0.f, 0.f);
    float4 a2 = make_float4(0.f, 0.f, 0.f, 0.f);

    #pragma unroll 2
    for (int jj = 0; jj < 16; jj += 2) {
      const int r0 = wave + 4 * jj, r1 = wave + 4 * (jj + 1);
      const float4* xr0 = reinterpret_cast<const float4*>(xb + (size_t)r0 * Dd);
      const float4* xr1 = reinterpret_cast<const float4*>(xb + (size_t)r1 * Dd);
      const float4 va0 = xr0[lane], vb0 = xr0[64 + lane];
      const float4 va1 = xr1[lane], vb1 = xr1[64 + lane];
      float d0 = DOT8(va0, vb0, u1, u2);
      float d1 = DOT8(va1, vb1, u1, u2);
      #pragma unroll
      for (int off = 32; off > 0; off >>= 1) {
        d0 += __shfl_xor(d0, off);
        d1 += __shfl_xor(d1, off);
      }
      const float s0 = d0 * SCALE, s1 = d1 * SCALE;
      if (lane == 0) { sb[r0] = s0; sb[r1] = s1; }
      const float e0 = __expf(s0), e1 = __expf(s1);
      a1.x += e0*va0.x + e1*va1.x; a1.y += e0*va0.y + e1*va1.y;
      a1.z += e0*va0.z + e1*va1.z; a1.w += e0*va0.w + e1*va1.w;
      a2.x += e0*vb0.x + e1*vb1.x; a2.y += e0*vb0.y + e1*vb1.y;
      a2.z += e0*vb0.z + e1*vb1.z; a2.w += e0*vb0.w + e1*vb1.w;
    }

    *reinterpret_cast<float4*>(&pacc[wave][lane * 4]) = a1;
    *reinterpret_cast<float4*>(&pacc[wave][256 + lane * 4]) = a2;
    __syncthreads();
    float* Pb = P + (size_t)blk * Dd;
    Pb[t]       = pacc[0][t]       + pacc[1][t]       + pacc[2][t]       + pacc[3][t];
    Pb[t + 256] = pacc[0][t + 256] + pacc[1][t + 256] + pacc[2][t + 256] + pacc[3][t + 256];
  }
  __threadfence();
  __syncthreads();
  if (t == 0) atomicAdd(&cnt3[b], 1);

  // ---------- Phase 4: softmax + aggregate (block i==0 of each batch) ----------
  if (i != 0) return;
  if (t == 0) { while (atomicAdd(&cnt3[b], 0) < BPB) __builtin_amdgcn_s_sleep(8); }
  __syncthreads();
  __threadfence();

  float v[4];
  for (int j = 0; j < 4; ++j) v[j] = s[(size_t)b * Nn + t + j * 256];
  float m = fmaxf(fmaxf(v[0], v[1]), fmaxf(v[2], v[3]));
  #pragma unroll
  for (int off = 32; off > 0; off >>= 1) m = fmaxf(m, __shfl_xor(m, off));
  if (lane == 0) lred[wave] = m;
  __syncthreads();
  m = fmaxf(fmaxf(lred[0], lred[1]), fmaxf(lred[2], lred[3]));
  __syncthreads();

  float e[4];
  float sum = 0.f;
  for (int j = 0; j < 4; ++j) { e[j] = expf(v[j] - m); sum += e[j]; }
  #pragma unroll
  for (int off = 32; off > 0; off >>= 1) sum += __shfl_xor(sum, off);
  if (lane == 0) lred[wave] = sum;
  __syncthreads();
  sum = lred[0] + lred[1] + lred[2] + lred[3];
  const float inv = 1.0f / sum;
  for (int j = 0; j < 4; ++j) w[(size_t)b * Nn + t + j * 256] = e[j] * inv;

  const float coef = expf(-m) * inv;   // P used exp(s) unshifted
  float g0 = 0.f, g1 = 0.f;
  #pragma unroll
  for (int j = 0; j < BPB; ++j) {
    g0 += P[(size_t)(b * BPB + j) * Dd + t];
    g1 += P[(size_t)(b * BPB + j) * Dd + t + 256];
  }
  agg[(size_t)b * Dd + t]       = g0 * coef;
  agg[(size_t)b * Dd + t + 256] = g1 * coef;
}

}  // namespace

extern "C" void kernel_launch(void* const* d_in, const int* in_sizes, int n_in,
                              void* d_out, int out_size, void* d_ws, size_t ws_size,
                              hipStream_t stream) {
  const float* x  = (const float*)d_in[0];
  const float* Wq = (const float*)d_in[1];
  const float* Wk = (const float*)d_in[3];
  const float* bk = (const float*)d_in[4];

  float* out = (float*)d_out;
  float* agg = out;                       // [B][D]
  float* w   = out + (size_t)Bsz * Dd;    // [B][N]

  // workspace (floats): part | upart | s | P | counters   (~8.4 MiB)
  float* part  = (float*)d_ws;                           // NBLK*2*Dd = 1,048,576
  float* upart = part + (size_t)NBLK * 2 * Dd;           // NBLK*Dd   =   524,288
  float* s     = upart + (size_t)NBLK * Dd;              // B*N       =    65,536
  float* P     = s + (size_t)Bsz * Nn;                   // NBLK*Dd   =   524,288
  int*   cnt   = (int*)(P + (size_t)NBLK * Dd);          // 3*B ints
  int* cnt1 = cnt, *cnt2 = cnt + Bsz, *cnt3 = cnt + 2 * Bsz;

  hipMemsetAsync(cnt, 0, 3 * Bsz * sizeof(int), stream);
  k_all<<<NBLK, 256, 0, stream>>>(x, Wq, Wk, bk, part, upart, s, P, w, agg,
                                  cnt1, cnt2, cnt3);
}

// Round 7
// 63.606 us; speedup vs baseline: 11.3814x; 11.3814x over previous
//
#include <hip/hip_runtime.h>
#include <math.h>

namespace {

constexpr int Bsz = 64;
constexpr int Nn  = 1024;
constexpr int Dd  = 512;
constexpr int NCH = 32;            // n-chunks for column-sum pass
constexpr int RPC = Nn / NCH;      // 32 rows per chunk
constexpr int SCH = 32;            // n-chunks for fused pass
constexpr int SRW = Nn / SCH;      // 32 rows per fused block
constexpr int GCH = 8;             // e-slices for prep (64 rows each)
constexpr float SCALE = 0.044194173824159216f;  // 1/sqrt(512)

// Pass 1: partial column sums of x. grid(B, NCH), block 128. HBM/L3-bound.
__global__ __launch_bounds__(128) void k_colsum(const float* __restrict__ x,
                                                float* __restrict__ part) {
  const int b = blockIdx.x, ch = blockIdx.y, t = threadIdx.x;
  const float* base = x + ((size_t)b * Nn + (size_t)ch * RPC) * Dd;
  float4 acc = make_float4(0.f, 0.f, 0.f, 0.f);
  #pragma unroll 8
  for (int n = 0; n < RPC; ++n) {
    float4 v = *reinterpret_cast<const float4*>(base + (size_t)n * Dd + t * 4);
    acc.x += v.x; acc.y += v.y; acc.z += v.z; acc.w += v.w;
  }
  *reinterpret_cast<float4*>(part + (size_t)(b * NCH + ch) * Dd + t * 4) = acc;
}

// Pass 2 (merged prep): block (b,g): wave-split part->xbar, kbar slice via
// wave-per-row dots, then u-partial: upart[b][g][d] = sum_{e in slice} kbar_e*Wq[e][d].
// grid(B, GCH), block 256 (4 waves). (c = bq.kbar dropped: softmax shift-inv.)
__global__ __launch_bounds__(256) void k_prep2(const float* __restrict__ part,
                                               const float* __restrict__ Wq,
                                               const float* __restrict__ Wk,
                                               const float* __restrict__ bk,
                                               float* __restrict__ upart) {
  const int b = blockIdx.x, g = blockIdx.y, t = threadIdx.x;
  const int wave = t >> 6, lane = t & 63;
  __shared__ __align__(16) float xbar[Dd];
  __shared__ __align__(16) float wred[4][Dd];
  __shared__ float kb[64];

  // wave-split xbar reduce: wave w sums chunks [w*8, w*8+8), lane covers 8 cols
  {
    float4 a0 = make_float4(0.f, 0.f, 0.f, 0.f);
    float4 a1 = make_float4(0.f, 0.f, 0.f, 0.f);
    const float* pb = part + ((size_t)b * NCH + wave * 8) * Dd + lane * 8;
    #pragma unroll
    for (int ch = 0; ch < 8; ++ch) {
      const float4 v0 = *reinterpret_cast<const float4*>(pb + (size_t)ch * Dd);
      const float4 v1 = *reinterpret_cast<const float4*>(pb + (size_t)ch * Dd + 4);
      a0.x += v0.x; a0.y += v0.y; a0.z += v0.z; a0.w += v0.w;
      a1.x += v1.x; a1.y += v1.y; a1.z += v1.z; a1.w += v1.w;
    }
    *reinterpret_cast<float4*>(&wred[wave][lane * 8])     = a0;
    *reinterpret_cast<float4*>(&wred[wave][lane * 8 + 4]) = a1;
  }
  __syncthreads();
  xbar[t]       = (wred[0][t]       + wred[1][t]       + wred[2][t]       + wred[3][t])       * (1.0f / Nn);
  xbar[t + 256] = (wred[0][t + 256] + wred[1][t + 256] + wred[2][t + 256] + wred[3][t + 256]) * (1.0f / Nn);
  __syncthreads();

  const float4 xv1 = *reinterpret_cast<const float4*>(xbar + lane * 4);
  const float4 xv2 = *reinterpret_cast<const float4*>(xbar + 256 + lane * 4);

  // wave handles slice rows [wave*16, wave*16+16), 2 in flight
  for (int i = 0; i < 16; i += 2) {
    const int l0 = wave * 16 + i, l1 = l0 + 1;
    const int e0 = g * 64 + l0, e1 = e0 + 1;
    const float4* r0 = reinterpret_cast<const float4*>(Wk + (size_t)e0 * Dd);
    const float4* r1 = reinterpret_cast<const float4*>(Wk + (size_t)e1 * Dd);
    const float4 a0 = r0[lane], b0 = r0[64 + lane];
    const float4 a1 = r1[lane], b1 = r1[64 + lane];
    float d0 = a0.x*xv1.x + a0.y*xv1.y + a0.z*xv1.z + a0.w*xv1.w
             + b0.x*xv2.x + b0.y*xv2.y + b0.z*xv2.z + b0.w*xv2.w;
    float d1 = a1.x*xv1.x + a1.y*xv1.y + a1.z*xv1.z + a1.w*xv1.w
             + b1.x*xv2.x + b1.y*xv2.y + b1.z*xv2.z + b1.w*xv2.w;
    #pragma unroll
    for (int off = 32; off > 0; off >>= 1) {
      d0 += __shfl_xor(d0, off);
      d1 += __shfl_xor(d1, off);
    }
    if (lane == 0) { kb[l0] = bk[e0] + d0; kb[l1] = bk[e1] + d1; }
  }
  __syncthreads();

  // u-partial for this slice: thread t covers d = t and d = t+256.
  const float* Wbase = Wq + (size_t)(g * 64) * Dd;
  float a0 = 0.f, a1 = 0.f, a2 = 0.f, a3 = 0.f;
  #pragma unroll 8
  for (int e = 0; e < 64; e += 2) {
    const float k0 = kb[e], k1 = kb[e + 1];
    a0 += k0 * Wbase[(size_t)e * Dd + t];
    a1 += k0 * Wbase[(size_t)e * Dd + t + 256];
    a2 += k1 * Wbase[(size_t)(e + 1) * Dd + t];
    a3 += k1 * Wbase[(size_t)(e + 1) * Dd + t + 256];
  }
  float* ub = upart + (size_t)(b * GCH + g) * Dd;
  ub[t]       = a0 + a2;
  ub[t + 256] = a1 + a3;
}

// Pass 3 (fused, branch-free): s[b,n] = x_n.u_b * SCALE; accumulate exp(s_n)*x_n.
// grid(B, SCH), block 256 (4 waves, 8 rows each, 2 in flight).
__global__ __launch_bounds__(256) void k_fused(const float* __restrict__ x,
                                               const float* __restrict__ upart,
                                               float* __restrict__ s,
                                               float* __restrict__ P) {
  const int b = blockIdx.x, ch = blockIdx.y, t = threadIdx.x;
  const int wave = t >> 6, lane = t & 63;

  // u = sum of GCH partials (tiny L2 reads)
  float4 u1 = make_float4(0.f, 0.f, 0.f, 0.f);
  float4 u2 = make_float4(0.f, 0.f, 0.f, 0.f);
  #pragma unroll
  for (int h = 0; h < GCH; ++h) {
    const float* ub = upart + (size_t)(b * GCH + h) * Dd;
    const float4 p1 = *reinterpret_cast<const float4*>(ub + lane * 4);
    const float4 p2 = *reinterpret_cast<const float4*>(ub + 256 + lane * 4);
    u1.x += p1.x; u1.y += p1.y; u1.z += p1.z; u1.w += p1.w;
    u2.x += p2.x; u2.y += p2.y; u2.z += p2.z; u2.w += p2.w;
  }

  const float* xb = x + ((size_t)b * Nn + (size_t)ch * SRW) * Dd;
  float* sb = s + (size_t)b * Nn + (size_t)ch * SRW;

  float4 a1 = make_float4(0.f, 0.f, 0.f, 0.f);
  float4 a2 = make_float4(0.f, 0.f, 0.f, 0.f);

  #pragma unroll 2
  for (int i = 0; i < 8; i += 2) {
    const int r0 = wave + 4 * i, r1 = wave + 4 * (i + 1);
    const float4* xr0 = reinterpret_cast<const float4*>(xb + (size_t)r0 * Dd);
    const float4* xr1 = reinterpret_cast<const float4*>(xb + (size_t)r1 * Dd);
    const float4 va0 = xr0[lane], vb0 = xr0[64 + lane];
    const float4 va1 = xr1[lane], vb1 = xr1[64 + lane];
    float d0 = va0.x*u1.x + va0.y*u1.y + va0.z*u1.z + va0.w*u1.w
             + vb0.x*u2.x + vb0.y*u2.y + vb0.z*u2.z + vb0.w*u2.w;
    float d1 = va1.x*u1.x + va1.y*u1.y + va1.z*u1.z + va1.w*u1.w
             + vb1.x*u2.x + vb1.y*u2.y + vb1.z*u2.z + vb1.w*u2.w;
    #pragma unroll
    for (int off = 32; off > 0; off >>= 1) {
      d0 += __shfl_xor(d0, off);
      d1 += __shfl_xor(d1, off);
    }
    const float s0 = d0 * SCALE, s1 = d1 * SCALE;
    if (lane == 0) { sb[r0] = s0; sb[r1] = s1; }
    const float e0 = __expf(s0), e1 = __expf(s1);
    a1.x += e0*va0.x + e1*va1.x; a1.y += e0*va0.y + e1*va1.y;
    a1.z += e0*va0.z + e1*va1.z; a1.w += e0*va0.w + e1*va1.w;
    a2.x += e0*vb0.x + e1*vb1.x; a2.y += e0*vb0.y + e1*vb1.y;
    a2.z += e0*vb0.z + e1*vb1.z; a2.w += e0*vb0.w + e1*vb1.w;
  }

  __shared__ __align__(16) float pacc[4][Dd];
  *reinterpret_cast<float4*>(&pacc[wave][lane * 4]) = a1;
  *reinterpret_cast<float4*>(&pacc[wave][256 + lane * 4]) = a2;
  __syncthreads();
  float* Pb = P + (size_t)(b * SCH + ch) * Dd;
  Pb[t]       = pacc[0][t]       + pacc[1][t]       + pacc[2][t]       + pacc[3][t];
  Pb[t + 256] = pacc[0][t + 256] + pacc[1][t + 256] + pacc[2][t + 256] + pacc[3][t + 256];
}

// Pass 4: w = exp(s)/Z (no max needed, |s| small); agg = (sum_ch P_ch)/Z.
// grid(B), 256 thr.
__global__ __launch_bounds__(256) void k_final(const float* __restrict__ s,
                                               const float* __restrict__ P,
                                               float* __restrict__ w,
                                               float* __restrict__ agg) {
  const int b = blockIdx.x, t = threadIdx.x;
  const int wave = t >> 6, lane = t & 63;
  __shared__ float lred[4];

  float e[4];
  float sum = 0.f;
  #pragma unroll
  for (int i = 0; i < 4; ++i) {
    e[i] = expf(s[(size_t)b * Nn + t + i * 256]);
    sum += e[i];
  }
  #pragma unroll
  for (int off = 32; off > 0; off >>= 1) sum += __shfl_xor(sum, off);
  if (lane == 0) lred[wave] = sum;
  __syncthreads();
  sum = lred[0] + lred[1] + lred[2] + lred[3];
  const float inv = 1.0f / sum;
  #pragma unroll
  for (int i = 0; i < 4; ++i) w[(size_t)b * Nn + t + i * 256] = e[i] * inv;

  float g0 = 0.f, g1 = 0.f;
  #pragma unroll 8
  for (int chh = 0; chh < SCH; ++chh) {
    g0 += P[(size_t)(b * SCH + chh) * Dd + t];
    g1 += P[(size_t)(b * SCH + chh) * Dd + t + 256];
  }
  agg[(size_t)b * Dd + t]       = g0 * inv;
  agg[(size_t)b * Dd + t + 256] = g1 * inv;
}

}  // namespace

extern "C" void kernel_launch(void* const* d_in, const int* in_sizes, int n_in,
                              void* d_out, int out_size, void* d_ws, size_t ws_size,
                              hipStream_t stream) {
  const float* x  = (const float*)d_in[0];
  const float* Wq = (const float*)d_in[1];
  const float* Wk = (const float*)d_in[3];
  const float* bk = (const float*)d_in[4];

  float* out = (float*)d_out;
  float* agg = out;                       // [B][D]
  float* w   = out + (size_t)Bsz * Dd;    // [B][N]

  // workspace (floats): part | upart | s | P   (~9.5 MiB)
  float* part  = (float*)d_ws;                          // B*NCH*D
  float* upart = part + (size_t)Bsz * NCH * Dd;         // B*GCH*D
  float* s     = upart + (size_t)Bsz * GCH * Dd;        // B*N
  float* P     = s + (size_t)Bsz * Nn;                  // B*SCH*D

  k_colsum<<<dim3(Bsz, NCH), 128, 0, stream>>>(x, part);
  k_prep2 <<<dim3(Bsz, GCH), 256, 0, stream>>>(part, Wq, Wk, bk, upart);
  k_fused <<<dim3(Bsz, SCH), 256, 0, stream>>>(x, upart, s, P);
  k_final <<<Bsz, 256, 0, stream>>>(s, P, w, agg);
}

// Round 8
// 62.126 us; speedup vs baseline: 11.6525x; 1.0238x over previous
//
#include <hip/hip_runtime.h>
#include <math.h>

namespace {

constexpr int Bsz = 64;
constexpr int Nn  = 1024;
constexpr int Dd  = 512;
constexpr int NCH = 8;             // n-chunks for column-sum pass (128 rows each)
constexpr int PPB = NCH * 2;       // partials per batch (2 parities per chunk) = 16
constexpr int SCH = 16;            // n-chunks for fused pass (64 rows each)
constexpr int SRW = Nn / SCH;      // 64 rows per fused block
constexpr int GCH = 8;             // e-slices for prep (64 rows each)
constexpr float SCALE = 0.044194173824159216f;  // 1/sqrt(512)

// Pass 1: partial column sums of x. grid(NCH, B), block 256 (8 waves).
// Block (i,b) streams rows [i*128, i*128+128) contiguously (256 KB).
__global__ __launch_bounds__(256) void k_colsum(const float* __restrict__ x,
                                                float* __restrict__ part) {
  const int i = blockIdx.x, b = blockIdx.y, t = threadIdx.x;
  const int col = (t & 127) * 4;   // 4 columns per thread
  const int p = t >> 7;            // row parity
  const float* xb = x + ((size_t)b * Nn + (size_t)i * 128) * Dd;
  float4 acc = make_float4(0.f, 0.f, 0.f, 0.f);
  #pragma unroll 8
  for (int j = 0; j < 64; ++j) {
    const int n = j * 2 + p;
    const float4 v = *reinterpret_cast<const float4*>(xb + (size_t)n * Dd + col);
    acc.x += v.x; acc.y += v.y; acc.z += v.z; acc.w += v.w;
  }
  *reinterpret_cast<float4*>(part + ((size_t)(b * NCH + i) * 2 + p) * Dd + col) = acc;
}

// Pass 2 (merged prep): block (g,b): wave-split part->xbar, kbar slice via
// wave-per-row dots, then u-partial: upart[b][g][d] = sum_{e in slice} kbar_e*Wq[e][d].
// grid(GCH, B), block 256 (4 waves). (c = bq.kbar dropped: softmax shift-inv.)
__global__ __launch_bounds__(256) void k_prep2(const float* __restrict__ part,
                                               const float* __restrict__ Wq,
                                               const float* __restrict__ Wk,
                                               const float* __restrict__ bk,
                                               float* __restrict__ upart) {
  const int g = blockIdx.x, b = blockIdx.y, t = threadIdx.x;
  const int wave = t >> 6, lane = t & 63;
  __shared__ __align__(16) float xbar[Dd];
  __shared__ __align__(16) float wred[4][Dd];
  __shared__ float kb[64];

  // wave-split xbar reduce: wave w sums partials [w*4, w*4+4), lane covers 8 cols
  {
    float4 a0 = make_float4(0.f, 0.f, 0.f, 0.f);
    float4 a1 = make_float4(0.f, 0.f, 0.f, 0.f);
    const float* pb = part + ((size_t)b * PPB + wave * 4) * Dd + lane * 8;
    #pragma unroll
    for (int ch = 0; ch < 4; ++ch) {
      const float4 v0 = *reinterpret_cast<const float4*>(pb + (size_t)ch * Dd);
      const float4 v1 = *reinterpret_cast<const float4*>(pb + (size_t)ch * Dd + 4);
      a0.x += v0.x; a0.y += v0.y; a0.z += v0.z; a0.w += v0.w;
      a1.x += v1.x; a1.y += v1.y; a1.z += v1.z; a1.w += v1.w;
    }
    *reinterpret_cast<float4*>(&wred[wave][lane * 8])     = a0;
    *reinterpret_cast<float4*>(&wred[wave][lane * 8 + 4]) = a1;
  }
  __syncthreads();
  xbar[t]       = (wred[0][t]       + wred[1][t]       + wred[2][t]       + wred[3][t])       * (1.0f / Nn);
  xbar[t + 256] = (wred[0][t + 256] + wred[1][t + 256] + wred[2][t + 256] + wred[3][t + 256]) * (1.0f / Nn);
  __syncthreads();

  const float4 xv1 = *reinterpret_cast<const float4*>(xbar + lane * 4);
  const float4 xv2 = *reinterpret_cast<const float4*>(xbar + 256 + lane * 4);

  // wave handles slice rows [wave*16, wave*16+16), 2 in flight
  for (int i = 0; i < 16; i += 2) {
    const int l0 = wave * 16 + i, l1 = l0 + 1;
    const int e0 = g * 64 + l0, e1 = e0 + 1;
    const float4* r0 = reinterpret_cast<const float4*>(Wk + (size_t)e0 * Dd);
    const float4* r1 = reinterpret_cast<const float4*>(Wk + (size_t)e1 * Dd);
    const float4 a0 = r0[lane], b0 = r0[64 + lane];
    const float4 a1 = r1[lane], b1 = r1[64 + lane];
    float d0 = a0.x*xv1.x + a0.y*xv1.y + a0.z*xv1.z + a0.w*xv1.w
             + b0.x*xv2.x + b0.y*xv2.y + b0.z*xv2.z + b0.w*xv2.w;
    float d1 = a1.x*xv1.x + a1.y*xv1.y + a1.z*xv1.z + a1.w*xv1.w
             + b1.x*xv2.x + b1.y*xv2.y + b1.z*xv2.z + b1.w*xv2.w;
    #pragma unroll
    for (int off = 32; off > 0; off >>= 1) {
      d0 += __shfl_xor(d0, off);
      d1 += __shfl_xor(d1, off);
    }
    if (lane == 0) { kb[l0] = bk[e0] + d0; kb[l1] = bk[e1] + d1; }
  }
  __syncthreads();

  // u-partial for this slice: thread t covers d = t and d = t+256.
  const float* Wbase = Wq + (size_t)(g * 64) * Dd;
  float a0 = 0.f, a1 = 0.f, a2 = 0.f, a3 = 0.f;
  #pragma unroll 8
  for (int e = 0; e < 64; e += 2) {
    const float k0 = kb[e], k1 = kb[e + 1];
    a0 += k0 * Wbase[(size_t)e * Dd + t];
    a1 += k0 * Wbase[(size_t)e * Dd + t + 256];
    a2 += k1 * Wbase[(size_t)(e + 1) * Dd + t];
    a3 += k1 * Wbase[(size_t)(e + 1) * Dd + t + 256];
  }
  float* ub = upart + (size_t)(b * GCH + g) * Dd;
  ub[t]       = a0 + a2;
  ub[t + 256] = a1 + a3;
}

// Pass 3 (fused, branch-free): s[b,n] = x_n.u_b * SCALE; accumulate exp(s_n)*x_n.
// grid(SCH, B), block 256 (4 waves, 16 rows each, 2 in flight). 128 KB stream/block.
__global__ __launch_bounds__(256) void k_fused(const float* __restrict__ x,
                                               const float* __restrict__ upart,
                                               float* __restrict__ s,
                                               float* __restrict__ P) {
  const int ch = blockIdx.x, b = blockIdx.y, t = threadIdx.x;
  const int wave = t >> 6, lane = t & 63;

  // u = sum of GCH partials (tiny L2 reads)
  float4 u1 = make_float4(0.f, 0.f, 0.f, 0.f);
  float4 u2 = make_float4(0.f, 0.f, 0.f, 0.f);
  #pragma unroll
  for (int h = 0; h < GCH; ++h) {
    const float* ub = upart + (size_t)(b * GCH + h) * Dd;
    const float4 p1 = *reinterpret_cast<const float4*>(ub + lane * 4);
    const float4 p2 = *reinterpret_cast<const float4*>(ub + 256 + lane * 4);
    u1.x += p1.x; u1.y += p1.y; u1.z += p1.z; u1.w += p1.w;
    u2.x += p2.x; u2.y += p2.y; u2.z += p2.z; u2.w += p2.w;
  }

  const float* xb = x + ((size_t)b * Nn + (size_t)ch * SRW) * Dd;
  float* sb = s + (size_t)b * Nn + (size_t)ch * SRW;

  float4 a1 = make_float4(0.f, 0.f, 0.f, 0.f);
  float4 a2 = make_float4(0.f, 0.f, 0.f, 0.f);

  #pragma unroll 2
  for (int i = 0; i < 16; i += 2) {
    const int r0 = wave + 4 * i, r1 = wave + 4 * (i + 1);
    const float4* xr0 = reinterpret_cast<const float4*>(xb + (size_t)r0 * Dd);
    const float4* xr1 = reinterpret_cast<const float4*>(xb + (size_t)r1 * Dd);
    const float4 va0 = xr0[lane], vb0 = xr0[64 + lane];
    const float4 va1 = xr1[lane], vb1 = xr1[64 + lane];
    float d0 = va0.x*u1.x + va0.y*u1.y + va0.z*u1.z + va0.w*u1.w
             + vb0.x*u2.x + vb0.y*u2.y + vb0.z*u2.z + vb0.w*u2.w;
    float d1 = va1.x*u1.x + va1.y*u1.y + va1.z*u1.z + va1.w*u1.w
             + vb1.x*u2.x + vb1.y*u2.y + vb1.z*u2.z + vb1.w*u2.w;
    #pragma unroll
    for (int off = 32; off > 0; off >>= 1) {
      d0 += __shfl_xor(d0, off);
      d1 += __shfl_xor(d1, off);
    }
    const float s0 = d0 * SCALE, s1 = d1 * SCALE;
    if (lane == 0) { sb[r0] = s0; sb[r1] = s1; }
    const float e0 = __expf(s0), e1 = __expf(s1);
    a1.x += e0*va0.x + e1*va1.x; a1.y += e0*va0.y + e1*va1.y;
    a1.z += e0*va0.z + e1*va1.z; a1.w += e0*va0.w + e1*va1.w;
    a2.x += e0*vb0.x + e1*vb1.x; a2.y += e0*vb0.y + e1*vb1.y;
    a2.z += e0*vb0.z + e1*vb1.z; a2.w += e0*vb0.w + e1*vb1.w;
  }

  __shared__ __align__(16) float pacc[4][Dd];
  *reinterpret_cast<float4*>(&pacc[wave][lane * 4]) = a1;
  *reinterpret_cast<float4*>(&pacc[wave][256 + lane * 4]) = a2;
  __syncthreads();
  float* Pb = P + (size_t)(b * SCH + ch) * Dd;
  Pb[t]       = pacc[0][t]       + pacc[1][t]       + pacc[2][t]       + pacc[3][t];
  Pb[t + 256] = pacc[0][t + 256] + pacc[1][t + 256] + pacc[2][t + 256] + pacc[3][t + 256];
}

// Pass 4: w = exp(s)/Z (no max needed, |s| small); agg = (sum_ch P_ch)/Z.
// grid(B), 256 thr.
__global__ __launch_bounds__(256) void k_final(const float* __restrict__ s,
                                               const float* __restrict__ P,
                                               float* __restrict__ w,
                                               float* __restrict__ agg) {
  const int b = blockIdx.x, t = threadIdx.x;
  const int wave = t >> 6, lane = t & 63;
  __shared__ float lred[4];

  float e[4];
  float sum = 0.f;
  #pragma unroll
  for (int i = 0; i < 4; ++i) {
    e[i] = expf(s[(size_t)b * Nn + t + i * 256]);
    sum += e[i];
  }
  #pragma unroll
  for (int off = 32; off > 0; off >>= 1) sum += __shfl_xor(sum, off);
  if (lane == 0) lred[wave] = sum;
  __syncthreads();
  sum = lred[0] + lred[1] + lred[2] + lred[3];
  const float inv = 1.0f / sum;
  #pragma unroll
  for (int i = 0; i < 4; ++i) w[(size_t)b * Nn + t + i * 256] = e[i] * inv;

  float g0 = 0.f, g1 = 0.f;
  #pragma unroll 8
  for (int chh = 0; chh < SCH; ++chh) {
    g0 += P[(size_t)(b * SCH + chh) * Dd + t];
    g1 += P[(size_t)(b * SCH + chh) * Dd + t + 256];
  }
  agg[(size_t)b * Dd + t]       = g0 * inv;
  agg[(size_t)b * Dd + t + 256] = g1 * inv;
}

}  // namespace

extern "C" void kernel_launch(void* const* d_in, const int* in_sizes, int n_in,
                              void* d_out, int out_size, void* d_ws, size_t ws_size,
                              hipStream_t stream) {
  const float* x  = (const float*)d_in[0];
  const float* Wq = (const float*)d_in[1];
  const float* Wk = (const float*)d_in[3];
  const float* bk = (const float*)d_in[4];

  float* out = (float*)d_out;
  float* agg = out;                       // [B][D]
  float* w   = out + (size_t)Bsz * Dd;    // [B][N]

  // workspace (floats): part | upart | s | P   (~5.5 MiB)
  float* part  = (float*)d_ws;                          // B*PPB*D = 524288
  float* upart = part + (size_t)Bsz * PPB * Dd;         // B*GCH*D = 262144
  float* s     = upart + (size_t)Bsz * GCH * Dd;        // B*N     =  65536
  float* P     = s + (size_t)Bsz * Nn;                  // B*SCH*D = 524288

  k_colsum<<<dim3(NCH, Bsz), 256, 0, stream>>>(x, part);
  k_prep2 <<<dim3(GCH, Bsz), 256, 0, stream>>>(part, Wq, Wk, bk, upart);
  k_fused <<<dim3(SCH, Bsz), 256, 0, stream>>>(x, upart, s, P);
  k_final <<<Bsz, 256, 0, stream>>>(s, P, w, agg);
}